// Round 1
// baseline (2715.088 us; speedup 1.0000x reference)
//
#include <hip/hip_runtime.h>
#include <math.h>

#define N_NODES 20000
#define N_EDGES 320000
#define F_IN    128
#define E_IN    64
#define HID     64
#define NH      4
#define CH      64
#define HC      256   // NH*CH
#define L_LAYERS 4
#define OUT_DIM 32
#define EPB     8     // edges per block in edge_msg

// h0 = x @ node_W + node_b   [N,128]@[128,64]
__global__ __launch_bounds__(256) void node_enc(const float* __restrict__ x,
                                                const float* __restrict__ W,
                                                const float* __restrict__ b,
                                                float* __restrict__ h) {
    int base_node = blockIdx.x * 4;
    int t = threadIdx.x;
    __shared__ float xs[4][F_IN];
    for (int i = t; i < 4 * F_IN; i += 256) {
        int nn = base_node + i / F_IN;
        xs[i / F_IN][i % F_IN] = (nn < N_NODES) ? x[nn * F_IN + (i % F_IN)] : 0.f;
    }
    __syncthreads();
    int node = base_node + t / 64;
    int col  = t & 63;
    if (node >= N_NODES) return;
    float acc = b[col];
    const float* xr = xs[t / 64];
    for (int i = 0; i < F_IN; i++) acc += xr[i] * W[i * HID + col];
    h[node * HID + col] = acc;
}

// ea = edge_attr @ eenc_W + eenc_b   [E,64]@[64,64]
__global__ __launch_bounds__(256) void edge_enc(const float* __restrict__ ein,
                                                const float* __restrict__ W,
                                                const float* __restrict__ b,
                                                float* __restrict__ ea) {
    int base_e = blockIdx.x * 4;
    int t = threadIdx.x;
    __shared__ float s[4][E_IN];
    for (int i = t; i < 4 * E_IN; i += 256) {
        int ee = base_e + i / E_IN;
        s[i / E_IN][i % E_IN] = (ee < N_EDGES) ? ein[ee * E_IN + (i % E_IN)] : 0.f;
    }
    __syncthreads();
    int e = base_e + t / 64;
    if (e >= N_EDGES) return;
    int col = t & 63;
    float acc = b[col];
    const float* r = s[t / 64];
    for (int i = 0; i < E_IN; i++) acc += r[i] * W[i * HID + col];
    ea[e * E_IN + col] = acc;
}

// Per node: z = (do_ln ? relu(LN(h)) : h); q/k/v = z@W*+b* [256]; skip = z@Wskip+bskip [64]
__global__ __launch_bounds__(256) void node_qkvs(const float* __restrict__ h,
                                                 const float* __restrict__ Wq, const float* __restrict__ bq,
                                                 const float* __restrict__ Wk, const float* __restrict__ bk,
                                                 const float* __restrict__ Wv, const float* __restrict__ bv,
                                                 const float* __restrict__ Ws, const float* __restrict__ bs,
                                                 const float* __restrict__ g,  const float* __restrict__ be,
                                                 int do_ln,
                                                 float* __restrict__ q, float* __restrict__ k,
                                                 float* __restrict__ v, float* __restrict__ skip) {
    int n = blockIdx.x;
    int t = threadIdx.x;
    __shared__ float zs[HID];
    if (t < 64) {
        float val = h[n * HID + t];
        if (do_ln) {
            float mu = val;
            for (int o = 32; o > 0; o >>= 1) mu += __shfl_xor(mu, o);
            mu *= (1.f / 64.f);
            float d = val - mu;
            float var = d * d;
            for (int o = 32; o > 0; o >>= 1) var += __shfl_xor(var, o);
            var *= (1.f / 64.f);
            val = d * rsqrtf(var + 1e-5f) * g[t] + be[t];
            val = fmaxf(val, 0.f);
        }
        zs[t] = val;
    }
    __syncthreads();
    float accq = bq[t], acck = bk[t], accv = bv[t];
    float accs = (t < 64) ? bs[t] : 0.f;
    for (int i = 0; i < HID; i++) {
        float z = zs[i];
        accq += z * Wq[i * HC + t];
        acck += z * Wk[i * HC + t];
        accv += z * Wv[i * HC + t];
        if (t < 64) accs += z * Ws[i * HID + t];
    }
    q[n * HC + t] = accq;
    k[n * HC + t] = acck;
    v[n * HC + t] = accv;
    if (t < 64) skip[n * HID + t] = accs;
}

// Per edge: e = ea@We [256]; alpha_h = q[dst]·(k[src]+e)/8; EX=exp(alpha);
// atomic denom[dst,h]+=EX; atomic out_num[dst,:] += (v[src]+e)*EX
__global__ __launch_bounds__(256) void edge_msg(const int* __restrict__ srcs,
                                                const int* __restrict__ dsts,
                                                const float* __restrict__ ea,
                                                const float* __restrict__ We,
                                                const float* __restrict__ q,
                                                const float* __restrict__ k,
                                                const float* __restrict__ v,
                                                float* __restrict__ denom,
                                                float* __restrict__ out_num) {
    int e0 = blockIdx.x * EPB;
    int t = threadIdx.x;
    __shared__ float eas[EPB][E_IN];
    __shared__ float exs[EPB][NH];
    __shared__ int ss[EPB], ds[EPB];
    for (int i = t; i < EPB * E_IN; i += 256) {
        int e = e0 + i / E_IN;
        eas[i / E_IN][i % E_IN] = ea[e * E_IN + (i % E_IN)];
    }
    if (t < EPB) { ss[t] = srcs[e0 + t]; ds[t] = dsts[e0 + t]; }
    __syncthreads();

    float ej[EPB];
#pragma unroll
    for (int m = 0; m < EPB; m++) ej[m] = 0.f;
    for (int i = 0; i < E_IN; i++) {
        float w = We[i * HC + t];
#pragma unroll
        for (int m = 0; m < EPB; m++) ej[m] += eas[m][i] * w;
    }

    int head = t >> 6, lane = t & 63;
#pragma unroll
    for (int m = 0; m < EPB; m++) {
        int s_ = ss[m], d_ = ds[m];
        float kj = k[s_ * HC + t] + ej[m];
        float qj = q[d_ * HC + t];
        float al = qj * kj;
        for (int o = 32; o > 0; o >>= 1) al += __shfl_xor(al, o);
        if (lane == 0) {
            float ex = __expf(al * 0.125f);
            exs[m][head] = ex;
            atomicAdd(&denom[d_ * NH + head], ex);
        }
    }
    __syncthreads();
#pragma unroll
    for (int m = 0; m < EPB; m++) {
        int s_ = ss[m], d_ = ds[m];
        float msg = (v[s_ * HC + t] + ej[m]) * exs[m][head];
        atomicAdd(&out_num[d_ * HC + t], msg);
    }
}

// h_new = mean_h(out_num/(denom+eps)) + skip (+ h_old if add_res)
__global__ __launch_bounds__(256) void node_update(const float* __restrict__ out_num,
                                                   const float* __restrict__ denom,
                                                   const float* __restrict__ skip,
                                                   float* __restrict__ h, int add_res) {
    int idx = blockIdx.x * 256 + threadIdx.x;
    if (idx >= N_NODES * HID) return;
    int n = idx / HID, c = idx % HID;
    float acc = 0.f;
#pragma unroll
    for (int hh = 0; hh < NH; hh++)
        acc += out_num[n * HC + hh * CH + c] / (denom[n * NH + hh] + 1e-16f);
    acc *= (1.f / NH);
    float val = acc + skip[idx];
    if (add_res) val += h[idx];
    h[idx] = val;
}

// out = relu(LN(h; g0,b0)) @ lin_W + lin_b
__global__ __launch_bounds__(64) void final_head(const float* __restrict__ h,
                                                 const float* __restrict__ g,
                                                 const float* __restrict__ b,
                                                 const float* __restrict__ W,
                                                 const float* __restrict__ bias,
                                                 float* __restrict__ out) {
    int n = blockIdx.x;
    int t = threadIdx.x;  // 64
    float val = h[n * HID + t];
    float mu = val;
    for (int o = 32; o > 0; o >>= 1) mu += __shfl_xor(mu, o);
    mu *= (1.f / 64.f);
    float d = val - mu;
    float var = d * d;
    for (int o = 32; o > 0; o >>= 1) var += __shfl_xor(var, o);
    var *= (1.f / 64.f);
    float z = fmaxf(d * rsqrtf(var + 1e-5f) * g[t] + b[t], 0.f);
    __shared__ float zs[HID];
    zs[t] = z;
    __syncthreads();
    if (t < OUT_DIM) {
        float acc = bias[t];
        for (int i = 0; i < HID; i++) acc += zs[i] * W[i * OUT_DIM + t];
        out[n * OUT_DIM + t] = acc;
    }
}

extern "C" void kernel_launch(void* const* d_in, const int* in_sizes, int n_in,
                              void* d_out, int out_size, void* d_ws, size_t ws_size,
                              hipStream_t stream) {
    const float* x      = (const float*)d_in[0];
    const int*   ei     = (const int*)d_in[1];
    const float* eattr  = (const float*)d_in[2];
    const float* node_W = (const float*)d_in[3];
    const float* node_b = (const float*)d_in[4];
    const float* eenc_W = (const float*)d_in[5];
    const float* eenc_b = (const float*)d_in[6];
    const float* Wq     = (const float*)d_in[7];
    const float* bq     = (const float*)d_in[8];
    const float* Wk     = (const float*)d_in[9];
    const float* bk     = (const float*)d_in[10];
    const float* Wv     = (const float*)d_in[11];
    const float* bv     = (const float*)d_in[12];
    const float* We     = (const float*)d_in[13];
    const float* Wskip  = (const float*)d_in[14];
    const float* bskip  = (const float*)d_in[15];
    const float* ln_g   = (const float*)d_in[16];
    const float* ln_b   = (const float*)d_in[17];
    const float* lin_W  = (const float*)d_in[18];
    const float* lin_b  = (const float*)d_in[19];
    float* out = (float*)d_out;

    const int* src = ei;            // edge_index[0]
    const int* dst = ei + N_EDGES;  // edge_index[1]

    float* ws = (float*)d_ws;
    float* h       = ws; ws += N_NODES * HID;      //  5.12 MB
    float* ea      = ws; ws += N_EDGES * E_IN;     // 81.92 MB
    float* q       = ws; ws += N_NODES * HC;       // 20.48 MB
    float* k       = ws; ws += N_NODES * HC;       // 20.48 MB
    float* v       = ws; ws += N_NODES * HC;       // 20.48 MB
    float* skip    = ws; ws += N_NODES * HID;      //  5.12 MB
    float* denom   = ws; ws += N_NODES * NH;       //  0.32 MB
    float* out_num = ws; ws += N_NODES * HC;       // 20.48 MB

    node_enc<<<N_NODES / 4, 256, 0, stream>>>(x, node_W, node_b, h);
    edge_enc<<<N_EDGES / 4, 256, 0, stream>>>(eattr, eenc_W, eenc_b, ea);

    for (int l = 0; l < L_LAYERS; l++) {
        node_qkvs<<<N_NODES, 256, 0, stream>>>(
            h,
            Wq + l * HID * HC, bq + l * HC,
            Wk + l * HID * HC, bk + l * HC,
            Wv + l * HID * HC, bv + l * HC,
            Wskip + l * HID * HID, bskip + l * HID,
            ln_g + l * HID, ln_b + l * HID,
            (l > 0) ? 1 : 0,
            q, k, v, skip);
        hipMemsetAsync(denom, 0, N_NODES * NH * sizeof(float), stream);
        hipMemsetAsync(out_num, 0, N_NODES * HC * sizeof(float), stream);
        edge_msg<<<N_EDGES / EPB, 256, 0, stream>>>(
            src, dst, ea, We + l * HID * HC, q, k, v, denom, out_num);
        node_update<<<(N_NODES * HID + 255) / 256, 256, 0, stream>>>(
            out_num, denom, skip, h, (l > 0) ? 1 : 0);
    }

    final_head<<<N_NODES, 64, 0, stream>>>(h, ln_g, ln_b, lin_W, lin_b, out);
}

// Round 2
// 1167.863 us; speedup vs baseline: 2.3248x; 2.3248x over previous
//
#include <hip/hip_runtime.h>
#include <math.h>

#define N_NODES 20000
#define N_EDGES 320000
#define F_IN    128
#define E_IN    64
#define HID     64
#define NH      4
#define CH      64
#define HC      256   // NH*CH
#define L_LAYERS 4
#define OUT_DIM 32
#define NPB     8     // nodes per block in node_pre / node_post

// ---------------- one-time encoders ----------------

// h0 = x @ node_W + node_b   [N,128]@[128,64]
__global__ __launch_bounds__(256) void node_enc(const float* __restrict__ x,
                                                const float* __restrict__ W,
                                                const float* __restrict__ b,
                                                float* __restrict__ h) {
    int base_node = blockIdx.x * 4;
    int t = threadIdx.x;
    __shared__ float xs[4][F_IN];
    for (int i = t; i < 4 * F_IN; i += 256) {
        int nn = base_node + i / F_IN;
        xs[i / F_IN][i % F_IN] = (nn < N_NODES) ? x[nn * F_IN + (i % F_IN)] : 0.f;
    }
    __syncthreads();
    int node = base_node + t / 64;
    int col  = t & 63;
    if (node >= N_NODES) return;
    float acc = b[col];
    const float* xr = xs[t / 64];
    for (int i = 0; i < F_IN; i++) acc += xr[i] * W[i * HID + col];
    h[node * HID + col] = acc;
}

// ea = edge_attr @ eenc_W + eenc_b   [E,64]@[64,64]
__global__ __launch_bounds__(256) void edge_enc(const float* __restrict__ ein,
                                                const float* __restrict__ W,
                                                const float* __restrict__ b,
                                                float* __restrict__ ea) {
    int base_e = blockIdx.x * 4;
    int t = threadIdx.x;
    __shared__ float s[4][E_IN];
    for (int i = t; i < 4 * E_IN; i += 256) {
        int ee = base_e + i / E_IN;
        s[i / E_IN][i % E_IN] = (ee < N_EDGES) ? ein[ee * E_IN + (i % E_IN)] : 0.f;
    }
    __syncthreads();
    int e = base_e + t / 64;
    if (e >= N_EDGES) return;
    int col = t & 63;
    float acc = b[col];
    const float* r = s[t / 64];
    for (int i = 0; i < E_IN; i++) acc += r[i] * W[i * HID + col];
    ea[e * E_IN + col] = acc;
}

// ---------------- CSR build (once) ----------------

__global__ __launch_bounds__(256) void hist_dst(const int* __restrict__ dst,
                                                int* __restrict__ hist) {
    int e = blockIdx.x * 256 + threadIdx.x;
    if (e < N_EDGES) atomicAdd(&hist[dst[e]], 1);
}

// single-block exclusive scan of hist[0..N) -> row_ptr[0..N], cursor[0..N)
__global__ __launch_bounds__(1024) void scan_hist(const int* __restrict__ hist,
                                                  int* __restrict__ row_ptr,
                                                  int* __restrict__ cursor) {
    __shared__ int sums[1024];
    const int CHUNK = 20;  // 1024*20 = 20480 >= 20000
    int t = threadIdx.x;
    int base = t * CHUNK;
    int local[CHUNK];
    int s = 0;
    for (int i = 0; i < CHUNK; i++) {
        int idx = base + i;
        int vv = (idx < N_NODES) ? hist[idx] : 0;
        local[i] = s;
        s += vv;
    }
    sums[t] = s;
    __syncthreads();
    for (int off = 1; off < 1024; off <<= 1) {
        int v = (t >= off) ? sums[t - off] : 0;
        __syncthreads();
        sums[t] += v;
        __syncthreads();
    }
    int excl = (t == 0) ? 0 : sums[t - 1];
    for (int i = 0; i < CHUNK; i++) {
        int idx = base + i;
        if (idx < N_NODES) {
            int p = excl + local[i];
            row_ptr[idx] = p;
            cursor[idx] = p;
        }
    }
    if (t == 1023) row_ptr[N_NODES] = sums[1023];
}

__global__ __launch_bounds__(256) void scatter_edges(const int* __restrict__ src,
                                                     const int* __restrict__ dst,
                                                     int* __restrict__ cursor,
                                                     int* __restrict__ src_perm,
                                                     int* __restrict__ eid_perm) {
    int e = blockIdx.x * 256 + threadIdx.x;
    if (e >= N_EDGES) return;
    int d = dst[e];
    int pos = atomicAdd(&cursor[d], 1);
    src_perm[pos] = src[e];
    eid_perm[pos] = e;
}

// ---------------- per-layer constant: Wqe = Wq ⊙_head We ----------------
// Wqe[l][i][h*64+j] = sum_c Wq[l][i][h*64+c] * We[l][j][h*64+c]
// bqe[l][h*64+j]    = sum_c bq[l][h*64+c]    * We[l][j][h*64+c]
__global__ __launch_bounds__(256) void make_wqe(const float* __restrict__ Wq,
                                                const float* __restrict__ bq,
                                                const float* __restrict__ We,
                                                float* __restrict__ Wqe,
                                                float* __restrict__ bqe) {
    int l = blockIdx.x / HID;
    int i = blockIdx.x % HID;
    int t = threadIdx.x;           // h*64+j
    int h = t >> 6, j = t & 63;
    const float* WqL = Wq + (size_t)l * HID * HC;
    const float* WeL = We + (size_t)l * HID * HC;
    float acc = 0.f;
    for (int c = 0; c < CH; c++)
        acc += WqL[i * HC + h * CH + c] * WeL[j * HC + h * CH + c];
    Wqe[(size_t)l * HID * HC + i * HC + t] = acc;
    if (i == 0) {
        const float* bqL = bq + l * HC;
        float accb = 0.f;
        for (int c = 0; c < CH; c++)
            accb += bqL[h * CH + c] * WeL[j * HC + h * CH + c];
        bqe[l * HC + t] = accb;
    }
}

// ---------------- per-layer node pre-pass ----------------
// z = (do_ln ? relu(LN(h)) : h)
// q  = z@Wq+bq [N,HC] plain layout
// k,v= z@Wk+bk, z@Wv+bv  stored head-interleaved: k[n][c*4+h]  (float4/gather)
// qw = z@Wqe+bqe [N,HC] plain layout
// skip = z@Wskip+bskip
__global__ __launch_bounds__(256) void node_pre(const float* __restrict__ h,
        const float* __restrict__ Wq, const float* __restrict__ bq,
        const float* __restrict__ Wk, const float* __restrict__ bk,
        const float* __restrict__ Wv, const float* __restrict__ bv,
        const float* __restrict__ Wqe, const float* __restrict__ bqe,
        const float* __restrict__ Ws, const float* __restrict__ bs,
        const float* __restrict__ g, const float* __restrict__ be,
        int do_ln,
        float* __restrict__ q, float* __restrict__ k, float* __restrict__ v,
        float* __restrict__ qw, float* __restrict__ skip) {
    int t = threadIdx.x;
    int base = blockIdx.x * NPB;
    int lane = t & 63;
    __shared__ float zs[NPB][HID];
    for (int it = 0; it < 2; it++) {
        int m = (t >> 6) + it * 4;
        int n = base + m;
        float val = (n < N_NODES) ? h[n * HID + lane] : 0.f;
        if (do_ln) {
            float mu = val;
            for (int o = 32; o > 0; o >>= 1) mu += __shfl_xor(mu, o);
            mu *= (1.f / 64.f);
            float d = val - mu;
            float var = d * d;
            for (int o = 32; o > 0; o >>= 1) var += __shfl_xor(var, o);
            var *= (1.f / 64.f);
            val = fmaxf(d * rsqrtf(var + 1e-5f) * g[lane] + be[lane], 0.f);
        }
        zs[m][lane] = val;
    }
    __syncthreads();
    float aq[NPB], ak[NPB], av[NPB], aw[NPB], as_[NPB];
    float bqv = bq[t], bkv = bk[t], bvv = bv[t], bwv = bqe[t];
    float bsv = (t < 64) ? bs[t] : 0.f;
#pragma unroll
    for (int m = 0; m < NPB; m++) { aq[m]=bqv; ak[m]=bkv; av[m]=bvv; aw[m]=bwv; as_[m]=bsv; }
    for (int i = 0; i < HID; i++) {
        float wq = Wq[i * HC + t], wk = Wk[i * HC + t];
        float wv = Wv[i * HC + t], wqe = Wqe[i * HC + t];
        float wsv = (t < 64) ? Ws[i * HID + t] : 0.f;
#pragma unroll
        for (int m = 0; m < NPB; m++) {
            float z = zs[m][i];
            aq[m] += z * wq; ak[m] += z * wk; av[m] += z * wv;
            aw[m] += z * wqe; as_[m] += z * wsv;
        }
    }
    int h_ = t >> 6, c = t & 63;
#pragma unroll
    for (int m = 0; m < NPB; m++) {
        int n = base + m;
        if (n >= N_NODES) break;
        q[(size_t)n * HC + t]  = aq[m];
        qw[(size_t)n * HC + t] = aw[m];
        k[(size_t)n * HC + c * 4 + h_] = ak[m];   // head-interleaved
        v[(size_t)n * HC + c * 4 + h_] = av[m];
        if (t < 64) skip[n * HID + t] = as_[m];
    }
}

// ---------------- per-layer edge gather (1 wave = 1 dst node) ----------------
__global__ __launch_bounds__(256) void gather_edges(
        const int* __restrict__ row_ptr,
        const int* __restrict__ src_perm, const int* __restrict__ eid_perm,
        const float* __restrict__ ea,
        const float* __restrict__ k, const float* __restrict__ v,
        float* q_numv,      // in: q [n][hc], out: numv [n][hc]  (same buffer)
        float* qw_numea,    // in: qw [n][hc], out: numea [n][hc]
        float* __restrict__ den) {
    int wave = threadIdx.x >> 6;
    int lane = threadIdx.x & 63;
    int n = blockIdx.x * 4 + wave;
    if (n >= N_NODES) return;
    int e0 = row_ptr[n], e1 = row_ptr[n + 1];
    size_t nb = (size_t)n * HC;
    float qv0 = q_numv[nb + lane],        qv1 = q_numv[nb + 64 + lane];
    float qv2 = q_numv[nb + 128 + lane],  qv3 = q_numv[nb + 192 + lane];
    float qw0 = qw_numea[nb + lane],       qw1 = qw_numea[nb + 64 + lane];
    float qw2 = qw_numea[nb + 128 + lane], qw3 = qw_numea[nb + 192 + lane];
    float nv0 = 0.f, nv1 = 0.f, nv2 = 0.f, nv3 = 0.f;
    float ne0 = 0.f, ne1 = 0.f, ne2 = 0.f, ne3 = 0.f;
    float d0 = 0.f, d1 = 0.f, d2 = 0.f, d3 = 0.f;
    for (int e = e0; e < e1; e++) {
        int s_  = src_perm[e];
        int eid = eid_perm[e];
        float eaj = ea[(size_t)eid * E_IN + lane];
        float4 kk = *(const float4*)(k + (size_t)s_ * HC + lane * 4);
        float4 vv = *(const float4*)(v + (size_t)s_ * HC + lane * 4);
        float r0 = qv0 * kk.x + qw0 * eaj;
        float r1 = qv1 * kk.y + qw1 * eaj;
        float r2 = qv2 * kk.z + qw2 * eaj;
        float r3 = qv3 * kk.w + qw3 * eaj;
        for (int o = 32; o > 0; o >>= 1) {
            r0 += __shfl_xor(r0, o);
            r1 += __shfl_xor(r1, o);
            r2 += __shfl_xor(r2, o);
            r3 += __shfl_xor(r3, o);
        }
        float ex0 = __expf(r0 * 0.125f), ex1 = __expf(r1 * 0.125f);
        float ex2 = __expf(r2 * 0.125f), ex3 = __expf(r3 * 0.125f);
        nv0 += ex0 * vv.x; nv1 += ex1 * vv.y; nv2 += ex2 * vv.z; nv3 += ex3 * vv.w;
        ne0 += ex0 * eaj;  ne1 += ex1 * eaj;  ne2 += ex2 * eaj;  ne3 += ex3 * eaj;
        d0 += ex0; d1 += ex1; d2 += ex2; d3 += ex3;
    }
    // q/qw rows for this node are dead now; reuse as numv/numea
    q_numv[nb + lane] = nv0;        q_numv[nb + 64 + lane] = nv1;
    q_numv[nb + 128 + lane] = nv2;  q_numv[nb + 192 + lane] = nv3;
    qw_numea[nb + lane] = ne0;        qw_numea[nb + 64 + lane] = ne1;
    qw_numea[nb + 128 + lane] = ne2;  qw_numea[nb + 192 + lane] = ne3;
    if (lane == 0) {
        den[n * 4 + 0] = d0; den[n * 4 + 1] = d1;
        den[n * 4 + 2] = d2; den[n * 4 + 3] = d3;
    }
}

// ---------------- per-layer node post-pass ----------------
// out[h][c] = (numv[h][c] + sum_j numea[h][j]*We[j][h*64+c]) / den[h]
// h_new = mean_h(out) + skip (+ h_old if add_res)
__global__ __launch_bounds__(256) void node_post(
        const float* __restrict__ numv, const float* __restrict__ numea,
        const float* __restrict__ den, const float* __restrict__ We,
        const float* __restrict__ skip, float* __restrict__ h, int add_res) {
    int t = threadIdx.x;
    int h_ = t >> 6;
    int base = blockIdx.x * NPB;
    __shared__ float nes[NPB][HC];
    __shared__ float vals[NPB][HC];
    for (int i = t; i < NPB * HC; i += 256) {
        int m = i >> 8;
        nes[m][i & 255] = numea[(size_t)(base + m) * HC + (i & 255)];
    }
    __syncthreads();
    float acc[NPB];
#pragma unroll
    for (int m = 0; m < NPB; m++) acc[m] = 0.f;
    for (int j = 0; j < HID; j++) {
        float w = We[j * HC + t];
#pragma unroll
        for (int m = 0; m < NPB; m++) acc[m] += nes[m][h_ * CH + j] * w;
    }
#pragma unroll
    for (int m = 0; m < NPB; m++) {
        int n = base + m;
        float dd = den[n * 4 + h_] + 1e-16f;
        vals[m][t] = (numv[(size_t)n * HC + t] + acc[m]) / dd * 0.25f;
    }
    __syncthreads();
    for (int it = 0; it < 2; it++) {
        int idx = t + it * 256;          // 0..511 -> 8 nodes x 64 ch
        int m = idx >> 6, c2 = idx & 63;
        int n = base + m;
        float s = vals[m][c2] + vals[m][64 + c2] + vals[m][128 + c2] + vals[m][192 + c2];
        float val = s + skip[n * HID + c2];
        if (add_res) val += h[n * HID + c2];
        h[n * HID + c2] = val;
    }
}

// ---------------- final head ----------------
__global__ __launch_bounds__(64) void final_head(const float* __restrict__ h,
                                                 const float* __restrict__ g,
                                                 const float* __restrict__ b,
                                                 const float* __restrict__ W,
                                                 const float* __restrict__ bias,
                                                 float* __restrict__ out) {
    int n = blockIdx.x;
    int t = threadIdx.x;  // 64
    float val = h[n * HID + t];
    float mu = val;
    for (int o = 32; o > 0; o >>= 1) mu += __shfl_xor(mu, o);
    mu *= (1.f / 64.f);
    float d = val - mu;
    float var = d * d;
    for (int o = 32; o > 0; o >>= 1) var += __shfl_xor(var, o);
    var *= (1.f / 64.f);
    float z = fmaxf(d * rsqrtf(var + 1e-5f) * g[t] + b[t], 0.f);
    __shared__ float zs[HID];
    zs[t] = z;
    __syncthreads();
    if (t < OUT_DIM) {
        float acc = bias[t];
        for (int i = 0; i < HID; i++) acc += zs[i] * W[i * OUT_DIM + t];
        out[n * OUT_DIM + t] = acc;
    }
}

extern "C" void kernel_launch(void* const* d_in, const int* in_sizes, int n_in,
                              void* d_out, int out_size, void* d_ws, size_t ws_size,
                              hipStream_t stream) {
    const float* x      = (const float*)d_in[0];
    const int*   ei     = (const int*)d_in[1];
    const float* eattr  = (const float*)d_in[2];
    const float* node_W = (const float*)d_in[3];
    const float* node_b = (const float*)d_in[4];
    const float* eenc_W = (const float*)d_in[5];
    const float* eenc_b = (const float*)d_in[6];
    const float* Wq     = (const float*)d_in[7];
    const float* bq     = (const float*)d_in[8];
    const float* Wk     = (const float*)d_in[9];
    const float* bk     = (const float*)d_in[10];
    const float* Wv     = (const float*)d_in[11];
    const float* bv     = (const float*)d_in[12];
    const float* We     = (const float*)d_in[13];
    const float* Wskip  = (const float*)d_in[14];
    const float* bskip  = (const float*)d_in[15];
    const float* ln_g   = (const float*)d_in[16];
    const float* ln_b   = (const float*)d_in[17];
    const float* lin_W  = (const float*)d_in[18];
    const float* lin_b  = (const float*)d_in[19];
    float* out = (float*)d_out;

    const int* src = ei;            // edge_index[0]
    const int* dst = ei + N_EDGES;  // edge_index[1]

    float* ws = (float*)d_ws;
    float* h    = ws; ws += N_NODES * HID;        //  1.28M
    float* ea   = ws; ws += (size_t)N_EDGES * E_IN; // 20.48M
    float* q    = ws; ws += N_NODES * HC;         //  5.12M (aliased -> numv)
    float* k    = ws; ws += N_NODES * HC;
    float* v    = ws; ws += N_NODES * HC;
    float* qw   = ws; ws += N_NODES * HC;         //  (aliased -> numea)
    float* skip = ws; ws += N_NODES * HID;
    float* den  = ws; ws += N_NODES * NH;
    float* Wqe  = ws; ws += L_LAYERS * HID * HC;
    float* bqe  = ws; ws += L_LAYERS * HC;
    int* hist     = (int*)ws; ws += N_NODES;
    int* row_ptr  = (int*)ws; ws += N_NODES + 4;
    int* cursor   = (int*)ws; ws += N_NODES;
    int* src_perm = (int*)ws; ws += N_EDGES;
    int* eid_perm = (int*)ws; ws += N_EDGES;

    node_enc<<<(N_NODES + 3) / 4, 256, 0, stream>>>(x, node_W, node_b, h);
    edge_enc<<<(N_EDGES + 3) / 4, 256, 0, stream>>>(eattr, eenc_W, eenc_b, ea);

    hipMemsetAsync(hist, 0, N_NODES * sizeof(int), stream);
    hist_dst<<<(N_EDGES + 255) / 256, 256, 0, stream>>>(dst, hist);
    scan_hist<<<1, 1024, 0, stream>>>(hist, row_ptr, cursor);
    scatter_edges<<<(N_EDGES + 255) / 256, 256, 0, stream>>>(src, dst, cursor,
                                                            src_perm, eid_perm);
    make_wqe<<<L_LAYERS * HID, 256, 0, stream>>>(Wq, bq, We, Wqe, bqe);

    for (int l = 0; l < L_LAYERS; l++) {
        node_pre<<<(N_NODES + NPB - 1) / NPB, 256, 0, stream>>>(
            h,
            Wq + (size_t)l * HID * HC, bq + l * HC,
            Wk + (size_t)l * HID * HC, bk + l * HC,
            Wv + (size_t)l * HID * HC, bv + l * HC,
            Wqe + (size_t)l * HID * HC, bqe + l * HC,
            Wskip + (size_t)l * HID * HID, bskip + l * HID,
            ln_g + l * HID, ln_b + l * HID,
            (l > 0) ? 1 : 0,
            q, k, v, qw, skip);
        gather_edges<<<(N_NODES + 3) / 4, 256, 0, stream>>>(
            row_ptr, src_perm, eid_perm, ea, k, v, q, qw, den);
        node_post<<<(N_NODES + NPB - 1) / NPB, 256, 0, stream>>>(
            q, qw, den, We + (size_t)l * HID * HC, skip, h, (l > 0) ? 1 : 0);
    }

    final_head<<<N_NODES, 64, 0, stream>>>(h, ln_g, ln_b, lin_W, lin_b, out);
}